// Round 12
// baseline (192.699 us; speedup 1.0000x reference)
//
#include <hip/hip_runtime.h>
#include <math.h>

// Problem constants (fixed): B=4, C=256, H=64, W=128, D=4, 81 shifts, C/R=16
// out: [B, 81, H, W] fp32 (2,654,208 elements)
// ws (floats): [0) pooled 82,944  [82944) At 82,944

#define HH 64
#define WW 128
#define CC 256
#define BB 4

// ---------------------------------------------------------------------------
// Kernel A: pooled[b, s, c] = sum_{h,w} f1[b,c,h,w] * f2pad[b,c,h+i,w+j]
// One 576-thread block (9 waves) per (b,c) plane; thread (h=t/9, di=t%9)
// owns a full row. Round-21: DE-ROTATED stage-1. r2's lesson: the compiler
// re-serializes explicit register double-buffers but still PAYS their
// register cost (out_kernel r2: VGPR 64 vs 48 for identical schedules).
// The rotation here held f1c+f1n(32)+f2wc+f2wn(48) live -> ~100 VGPR ->
// only 2 blocks/CU resident (27-wave residency needs <=75 VGPR at 40KB
// LDS); plus 40 movs/seg = ~640cy/wave of pure copies. Now: plain per-seg
// {4 f1 float4 loads + 6 f2 LDS reads + 144 FMA}, same math (r0's clamped
// last-seg dup made seg 7 identical anyway). Expect VGPR ~65-70 -> 3
// blocks/CU and the mov tax gone.
// ---------------------------------------------------------------------------
__global__ __launch_bounds__(576) void corr_pool_kernel(
    const float* __restrict__ f1, const float* __restrict__ f2,
    float* __restrict__ pooled) {
  const int t  = threadIdx.x;
  const int bc = blockIdx.x;                    // b*256 + c
  const float* f1p = f1 + (size_t)bc * (HH * WW);
  const float* f2p = f2 + (size_t)bc * (HH * WW);

  __shared__ float4 f2s4[72 * 35];              // 40,320 B; reused for reduce

  // --- stage f2 plane with zero halo (single barrier) ---
  const float4 z4 = make_float4(0.f, 0.f, 0.f, 0.f);
  for (int u = t; u < 72 * 35; u += 576) {
    const int rl = u / 35, k = u - rl * 35;     // padded row, padded chunk
    const int gr = rl - 4;                      // f2 row
    float4 v = z4;
    if ((unsigned)gr < 64u && k >= 1 && k <= 32)
      v = *(const float4*)(f2p + (gr << 7) + ((k - 1) << 2));
    f2s4[u] = v;
  }
  __syncthreads();

  // --- stage 1: thread (h, di) accumulates s9[j] over its full row ---
  const int h  = t / 9;                         // 0..63
  const int di = t - h * 9;                     // 0..8
  const float4* f2row = &f2s4[(h + di) * 35];   // padded row h+di
  const float* f1row  = f1p + (h << 7);

  float s9[9];
#pragma unroll
  for (int j = 0; j < 9; ++j) s9[j] = 0.f;

  for (int seg = 0; seg < 8; ++seg) {
    alignas(16) float f1c[16], f2wc[24];
#pragma unroll
    for (int m = 0; m < 4; ++m)
      *(float4*)&f1c[4 * m] =
          *(const float4*)(f1row + (seg << 4) + (m << 2));
#pragma unroll
    for (int m = 0; m < 6; ++m)
      *(float4*)&f2wc[4 * m] = f2row[(seg << 2) + m];

#pragma unroll
    for (int k = 0; k < 16; ++k) {
      const float a = f1c[k];
#pragma unroll
      for (int j = 0; j < 9; ++j) s9[j] += a * f2wc[k + j];
    }
  }

  // --- stage 2: parallel column reduction (all 576 threads) ---
  __syncthreads();                              // stage-1 LDS reads done
  float* red  = (float*)f2s4;                   // [64][81]
  float* red2 = red + 64 * 81;                  // [7][81]
#pragma unroll
  for (int j = 0; j < 9; ++j) red[h * 81 + di * 9 + j] = s9[j];
  __syncthreads();

  if (t < 567) {                                // 7 groups x 81 cols
    const int col = t % 81, g = t / 81;
    const int r0 = g * 9, r1 = (g == 6) ? 64 : r0 + 9;
    float acc = 0.f;
#pragma unroll 3
    for (int rr = r0; rr < r1; ++rr) acc += red[rr * 81 + col];
    red2[g * 81 + col] = acc;
  }
  __syncthreads();

  if (t < 81) {
    float acc = 0.f;
#pragma unroll
    for (int g = 0; g < 7; ++g) acc += red2[g * 81 + t];
    const int b = bc >> 8, c = bc & 255;
    pooled[(size_t)(b * 81 + t) * 256 + c] = acc;   // raw sum (/8192 in B)
  }
}

// ---------------------------------------------------------------------------
// Kernel B: At[b, c, s] = sigmoid(MLP(pooled/8192)). Transposed output for
// kernel C's wave-uniform coefficient s_loads. UNCHANGED.
// ---------------------------------------------------------------------------
__global__ __launch_bounds__(256) void mlp_kernel(
    const float* __restrict__ pooled, const float* __restrict__ w1,
    const float* __restrict__ b1, const float* __restrict__ w2,
    const float* __restrict__ b2, float* __restrict__ At) {
  const int bs = blockIdx.x;                    // b*81 + s
  const int t  = threadIdx.x;
  const int b  = bs / 81;
  const int s  = bs - b * 81;
  __shared__ float p[256];
  __shared__ float hid[16];

  p[t] = pooled[(size_t)bs * 256 + t] * (1.0f / 8192.0f);
  __syncthreads();

  const int g = t >> 4, ln = t & 15;
  float acc = 0.f;
#pragma unroll
  for (int m = 0; m < 16; ++m) {
    const int c = (m << 4) + ln;
    acc += w1[(g << 8) + c] * p[c];
  }
  acc += __shfl_xor(acc, 1);
  acc += __shfl_xor(acc, 2);
  acc += __shfl_xor(acc, 4);
  acc += __shfl_xor(acc, 8);
  if (ln == 0) hid[g] = acc + b1[g];
  __syncthreads();

  float acc2 = b2[t];
#pragma unroll
  for (int k = 0; k < 16; ++k) acc2 += w2[(t << 4) + k] * hid[k];
  const float sv = 1.0f / (1.0f + __expf(-acc2));
  At[((size_t)(b * 256 + t)) * 81 + s] = sv;    // transposed: [b][c][81]
}

// ---------------------------------------------------------------------------
// Kernel C: out[b, i*9+j, h, w] =
//   (1/256) sum_c At[b,c,i*9+j]*f1[c,h,w]*f2[c,h+i-4,w+j-4]
// FROZEN at the round-11 half-fused form (best measured total, 188.9).
// Per-wave body is the r3 local optimum; r11's +11us vs r3 is L2-capacity
// (both halves per XCD) and is more than paid for by combine's removal.
// ---------------------------------------------------------------------------
__global__ __launch_bounds__(128, 4) void out_kernel(
    const float* __restrict__ f1, const float* __restrict__ f2,
    const float* __restrict__ At, float* __restrict__ out) {
  // bid = x + 8*(i + 9*tq); tile = tq*8 + x keeps i-siblings on one XCD
  const int bid  = blockIdx.x;                  // 0..1151
  const int x    = bid & 7;
  const int q    = bid >> 3;                    // 0..143
  const int i    = q % 9;
  const int tq   = q / 9;                       // 0..15
  const int tile = tq * 8 + x;                  // 0..127
  const int rt   = tile & 31;
  const int b    = tile >> 5;
  const int h0   = rt << 1;

  const int t    = threadIdx.x;
  const int wv   = t >> 6;                      // 0..1 = channel half
  const int lane = t & 63;
  const int r    = lane >> 5;                   // 0..1
  const int cidx = lane & 31;
  const int w0   = cidx << 2;
  const int h    = h0 + r;
  const int hr   = h + i - 4;
  const bool rowok = ((unsigned)hr < 64u);

  float acc[9][4];
#pragma unroll
  for (int j = 0; j < 9; ++j)
#pragma unroll
    for (int k = 0; k < 4; ++k) acc[j][k] = 0.f;

  if (rowok) {
    const int c0 = wv << 7;                     // 128-channel half base
    const float* pa1 = f1 + (size_t)b * (CC * 8192) + (size_t)c0 * 8192 +
                       (h << 7) + w0;
    const float* pa2 = f2 + (size_t)b * (CC * 8192) + (size_t)c0 * 8192 +
                       (hr << 7);
    const float* pb1 = pa1 + (size_t)64 * 8192; // paired channel c+64
    const float* pb2 = pa2 + (size_t)64 * 8192;
    const float* Aa  = At + (size_t)b * (CC * 81) + (size_t)c0 * 81 + i * 9;

    const bool vA  = (cidx > 0);
    const bool vC  = (cidx < 31);

    for (int c = 0; c < 64; ++c) {
      // --- 4 vector loads (two channels, center only) ---
      const float4 xa = *(const float4*)(pa1);
      const float4 aB = *(const float4*)(pa2 + w0);
      const float4 xb = *(const float4*)(pb1);
      const float4 bB = *(const float4*)(pb2 + w0);

      const float* ca = Aa + (size_t)c * 81;    // wave-uniform -> s_load
      const float* cb = ca + (size_t)64 * 81;

      const int adv = (c < 63) ? 8192 : 0;      // cndmask, no branch
      pa1 += adv; pa2 += adv; pb1 += adv; pb2 += adv;

      // --- neighbor window float4s from adjacent lanes (DS pipe) ---
      const float aAx = __shfl_up(aB.x, 1);
      const float aAy = __shfl_up(aB.y, 1);
      const float aAz = __shfl_up(aB.z, 1);
      const float aAw = __shfl_up(aB.w, 1);
      const float aCx = __shfl_down(aB.x, 1);
      const float aCy = __shfl_down(aB.y, 1);
      const float aCz = __shfl_down(aB.z, 1);
      const float aCw = __shfl_down(aB.w, 1);
      const float bAx = __shfl_up(bB.x, 1);
      const float bAy = __shfl_up(bB.y, 1);
      const float bAz = __shfl_up(bB.z, 1);
      const float bAw = __shfl_up(bB.w, 1);
      const float bCx = __shfl_down(bB.x, 1);
      const float bCy = __shfl_down(bB.y, 1);
      const float bCz = __shfl_down(bB.z, 1);
      const float bCw = __shfl_down(bB.w, 1);

      // --- channel a ---
      alignas(16) float f2ra[12];
      f2ra[0] = vA ? aAx : 0.f;
      f2ra[1] = vA ? aAy : 0.f;
      f2ra[2] = vA ? aAz : 0.f;
      f2ra[3] = vA ? aAw : 0.f;
      f2ra[4] = aB.x; f2ra[5] = aB.y; f2ra[6] = aB.z; f2ra[7] = aB.w;
      f2ra[8]  = vC ? aCx : 0.f;
      f2ra[9]  = vC ? aCy : 0.f;
      f2ra[10] = vC ? aCz : 0.f;
      f2ra[11] = vC ? aCw : 0.f;
      alignas(16) const float xxa[4] = {xa.x, xa.y, xa.z, xa.w};

#pragma unroll
      for (int j = 0; j < 9; ++j) {
        const float wj = ca[j];
#pragma unroll
        for (int k = 0; k < 4; ++k) acc[j][k] += wj * (xxa[k] * f2ra[k + j]);
      }

      // --- channel b (c+64) ---
      alignas(16) float f2rb[12];
      f2rb[0] = vA ? bAx : 0.f;
      f2rb[1] = vA ? bAy : 0.f;
      f2rb[2] = vA ? bAz : 0.f;
      f2rb[3] = vA ? bAw : 0.f;
      f2rb[4] = bB.x; f2rb[5] = bB.y; f2rb[6] = bB.z; f2rb[7] = bB.w;
      f2rb[8]  = vC ? bCx : 0.f;
      f2rb[9]  = vC ? bCy : 0.f;
      f2rb[10] = vC ? bCz : 0.f;
      f2rb[11] = vC ? bCw : 0.f;
      alignas(16) const float xxb[4] = {xb.x, xb.y, xb.z, xb.w};

#pragma unroll
      for (int j = 0; j < 9; ++j) {
        const float wj = cb[j];
#pragma unroll
        for (int k = 0; k < 4; ++k) acc[j][k] += wj * (xxb[k] * f2rb[k + j]);
      }
    }
  }

  // --- end-only cross-half reduction (one barrier, conflict-free) ---
  __shared__ float4 red[9][64];                 // 9,216 B
  if (wv == 1) {
#pragma unroll
    for (int j = 0; j < 9; ++j)
      red[j][lane] = make_float4(acc[j][0], acc[j][1], acc[j][2], acc[j][3]);
  }
  __syncthreads();

  if (wv == 0) {
    const float inv = 1.0f / 256.0f;
#pragma unroll
    for (int j = 0; j < 9; ++j) {
      const float4 p = red[j][lane];
      float4 o;
      o.x = (acc[j][0] + p.x) * inv;
      o.y = (acc[j][1] + p.y) * inv;
      o.z = (acc[j][2] + p.z) * inv;
      o.w = (acc[j][3] + p.w) * inv;
      *(float4*)(out + (((size_t)(b * 81 + i * 9 + j) * 64 + h) << 7) + w0) = o;
    }
  }
}

// ---------------------------------------------------------------------------
extern "C" void kernel_launch(void* const* d_in, const int* in_sizes, int n_in,
                              void* d_out, int out_size, void* d_ws, size_t ws_size,
                              hipStream_t stream) {
  const float* feat1 = (const float*)d_in[0];
  const float* feat2 = (const float*)d_in[1];
  const float* w1    = (const float*)d_in[2];
  const float* b1    = (const float*)d_in[3];
  const float* w2    = (const float*)d_in[4];
  const float* b2    = (const float*)d_in[5];
  float* out = (float*)d_out;

  float* pooled = (float*)d_ws;                 // 82,944 floats
  float* At     = pooled + 82944;               // 82,944 floats

  corr_pool_kernel<<<1024, 576, 0, stream>>>(feat1, feat2, pooled);
  mlp_kernel<<<4 * 81, 256, 0, stream>>>(pooled, w1, b1, w2, b2, At);
  out_kernel<<<1152, 128, 0, stream>>>(feat1, feat2, At, out);
}

// Round 13
// 190.255 us; speedup vs baseline: 1.0128x; 1.0128x over previous
//
#include <hip/hip_runtime.h>
#include <math.h>

// Problem constants (fixed): B=4, C=256, H=64, W=128, D=4, 81 shifts, C/R=16
// out: [B, 81, H, W] fp32 (2,654,208 elements)
// ws (floats): [0) pooled 82,944  [82944) At 82,944

#define HH 64
#define WW 128
#define CC 256
#define BB 4

// ---------------------------------------------------------------------------
// Kernel A: pooled[b, s, c] = sum_{h,w} f1[b,c,h,w] * f2pad[b,c,h+i,w+j]
// One 576-thread block (9 waves) per (b,c) plane; thread (h=t/9, di=t%9)
// owns a full row. REVERTED to the r0 ROTATED body: r12 proved the rotation
// is a live global-load pipeline (de-rotating cost +9us) -- the compiler
// keeps it because the f1 loads are long-latency globals, unlike r2's
// collapsed register-only rotation. FROZEN.
// ---------------------------------------------------------------------------
__global__ __launch_bounds__(576) void corr_pool_kernel(
    const float* __restrict__ f1, const float* __restrict__ f2,
    float* __restrict__ pooled) {
  const int t  = threadIdx.x;
  const int bc = blockIdx.x;                    // b*256 + c
  const float* f1p = f1 + (size_t)bc * (HH * WW);
  const float* f2p = f2 + (size_t)bc * (HH * WW);

  __shared__ float4 f2s4[72 * 35];              // 40,320 B; reused for reduce

  // --- stage f2 plane with zero halo (single barrier) ---
  const float4 z4 = make_float4(0.f, 0.f, 0.f, 0.f);
  for (int u = t; u < 72 * 35; u += 576) {
    const int rl = u / 35, k = u - rl * 35;     // padded row, padded chunk
    const int gr = rl - 4;                      // f2 row
    float4 v = z4;
    if ((unsigned)gr < 64u && k >= 1 && k <= 32)
      v = *(const float4*)(f2p + (gr << 7) + ((k - 1) << 2));
    f2s4[u] = v;
  }
  __syncthreads();

  // --- stage 1: thread (h, di) accumulates s9[j] over its full row ---
  const int h  = t / 9;                         // 0..63
  const int di = t - h * 9;                     // 0..8
  const float4* f2row = &f2s4[(h + di) * 35];   // padded row h+di
  const float* f1row  = f1p + (h << 7);

  float s9[9];
#pragma unroll
  for (int j = 0; j < 9; ++j) s9[j] = 0.f;

  alignas(16) float f1c[16], f2wc[24];
#pragma unroll
  for (int m = 0; m < 4; ++m)
    *(float4*)&f1c[4 * m] = *(const float4*)(f1row + (m << 2));
#pragma unroll
  for (int m = 0; m < 6; ++m) *(float4*)&f2wc[4 * m] = f2row[m];

  for (int seg = 0; seg < 8; ++seg) {
    const int nxt = (seg < 7) ? seg + 1 : 7;    // clamped (dup load on last)
    alignas(16) float f1n[16], f2wn[24];
#pragma unroll
    for (int m = 0; m < 4; ++m)
      *(float4*)&f1n[4 * m] =
          *(const float4*)(f1row + (nxt << 4) + (m << 2));
#pragma unroll
    for (int m = 0; m < 6; ++m) *(float4*)&f2wn[4 * m] = f2row[(nxt << 2) + m];

#pragma unroll
    for (int k = 0; k < 16; ++k) {
      const float a = f1c[k];
#pragma unroll
      for (int j = 0; j < 9; ++j) s9[j] += a * f2wc[k + j];
    }
#pragma unroll
    for (int m = 0; m < 16; ++m) f1c[m] = f1n[m];
#pragma unroll
    for (int m = 0; m < 24; ++m) f2wc[m] = f2wn[m];
  }

  // --- stage 2: parallel column reduction (all 576 threads) ---
  __syncthreads();                              // stage-1 LDS reads done
  float* red  = (float*)f2s4;                   // [64][81]
  float* red2 = red + 64 * 81;                  // [7][81]
#pragma unroll
  for (int j = 0; j < 9; ++j) red[h * 81 + di * 9 + j] = s9[j];
  __syncthreads();

  if (t < 567) {                                // 7 groups x 81 cols
    const int col = t % 81, g = t / 81;
    const int r0 = g * 9, r1 = (g == 6) ? 64 : r0 + 9;
    float acc = 0.f;
#pragma unroll 3
    for (int rr = r0; rr < r1; ++rr) acc += red[rr * 81 + col];
    red2[g * 81 + col] = acc;
  }
  __syncthreads();

  if (t < 81) {
    float acc = 0.f;
#pragma unroll
    for (int g = 0; g < 7; ++g) acc += red2[g * 81 + t];
    const int b = bc >> 8, c = bc & 255;
    pooled[(size_t)(b * 81 + t) * 256 + c] = acc;   // raw sum (/8192 in B)
  }
}

// ---------------------------------------------------------------------------
// Kernel B: At[b, c, s] = sigmoid(MLP(pooled/8192)). Transposed output for
// kernel C's wave-uniform coefficient s_loads. UNCHANGED.
// ---------------------------------------------------------------------------
__global__ __launch_bounds__(256) void mlp_kernel(
    const float* __restrict__ pooled, const float* __restrict__ w1,
    const float* __restrict__ b1, const float* __restrict__ w2,
    const float* __restrict__ b2, float* __restrict__ At) {
  const int bs = blockIdx.x;                    // b*81 + s
  const int t  = threadIdx.x;
  const int b  = bs / 81;
  const int s  = bs - b * 81;
  __shared__ float p[256];
  __shared__ float hid[16];

  p[t] = pooled[(size_t)bs * 256 + t] * (1.0f / 8192.0f);
  __syncthreads();

  const int g = t >> 4, ln = t & 15;
  float acc = 0.f;
#pragma unroll
  for (int m = 0; m < 16; ++m) {
    const int c = (m << 4) + ln;
    acc += w1[(g << 8) + c] * p[c];
  }
  acc += __shfl_xor(acc, 1);
  acc += __shfl_xor(acc, 2);
  acc += __shfl_xor(acc, 4);
  acc += __shfl_xor(acc, 8);
  if (ln == 0) hid[g] = acc + b1[g];
  __syncthreads();

  float acc2 = b2[t];
#pragma unroll
  for (int k = 0; k < 16; ++k) acc2 += w2[(t << 4) + k] * hid[k];
  const float sv = 1.0f / (1.0f + __expf(-acc2));
  At[((size_t)(b * 256 + t)) * 81 + s] = sv;    // transposed: [b][c][81]
}

// ---------------------------------------------------------------------------
// Kernel C: out[b, i*9+j, h, w] =
//   (1/256) sum_c At[b,c,i*9+j]*f1[c,h,w]*f2[c,h+i-4,w+j-4]
// Round-22: XCD PHASE-LOCALITY SWIZZLE (body byte-frozen from r11).
// Evidence: dur tracks FETCH across configs (r3: 86MB/63us; r11-12:
// 103MB/69-74us) -- the per-iteration chain is L2-miss-latency sensitive.
// Old mapping gave each XCD all 4 batches x 256 channels (~23MB >> 4MB L2).
// New: XCD x = bid&7 (round-robin dispatch) gets ONE b (x>>1) and ONE
// 16-tile row band (x&1), all 9 i, all channels. Its 144 equal-length
// blocks sweep c in lockstep -> instantaneous hot set ~72KB (two channels'
// row bands) -> L2-resident; each f1/f2 row fetched ~once per XCD pass.
// Predict: FETCH 103 -> ~75-80MB; dur -> 60-67 if latency theory holds,
// flat if not (then accept plateau).
// ---------------------------------------------------------------------------
__global__ __launch_bounds__(128, 4) void out_kernel(
    const float* __restrict__ f1, const float* __restrict__ f2,
    const float* __restrict__ At, float* __restrict__ out) {
  const int bid  = blockIdx.x;                  // 0..1151
  const int x    = bid & 7;                     // XCD id (bid%8 round-robin)
  const int u    = bid >> 3;                    // 0..143 within XCD
  const int i    = u % 9;
  const int loc  = u / 9;                       // 0..15
  const int b    = x >> 1;                      // batch per XCD-pair
  const int rt   = ((x & 1) << 4) + loc;        // 16-row-tile band per XCD
  const int h0   = rt << 1;

  const int t    = threadIdx.x;
  const int wv   = t >> 6;                      // 0..1 = channel half
  const int lane = t & 63;
  const int r    = lane >> 5;                   // 0..1
  const int cidx = lane & 31;
  const int w0   = cidx << 2;
  const int h    = h0 + r;
  const int hr   = h + i - 4;
  const bool rowok = ((unsigned)hr < 64u);

  float acc[9][4];
#pragma unroll
  for (int j = 0; j < 9; ++j)
#pragma unroll
    for (int k = 0; k < 4; ++k) acc[j][k] = 0.f;

  if (rowok) {
    const int c0 = wv << 7;                     // 128-channel half base
    const float* pa1 = f1 + (size_t)b * (CC * 8192) + (size_t)c0 * 8192 +
                       (h << 7) + w0;
    const float* pa2 = f2 + (size_t)b * (CC * 8192) + (size_t)c0 * 8192 +
                       (hr << 7);
    const float* pb1 = pa1 + (size_t)64 * 8192; // paired channel c+64
    const float* pb2 = pa2 + (size_t)64 * 8192;
    const float* Aa  = At + (size_t)b * (CC * 81) + (size_t)c0 * 81 + i * 9;

    const bool vA  = (cidx > 0);
    const bool vC  = (cidx < 31);

    for (int c = 0; c < 64; ++c) {
      // --- 4 vector loads (two channels, center only) ---
      const float4 xa = *(const float4*)(pa1);
      const float4 aB = *(const float4*)(pa2 + w0);
      const float4 xb = *(const float4*)(pb1);
      const float4 bB = *(const float4*)(pb2 + w0);

      const float* ca = Aa + (size_t)c * 81;    // wave-uniform -> s_load
      const float* cb = ca + (size_t)64 * 81;

      const int adv = (c < 63) ? 8192 : 0;      // cndmask, no branch
      pa1 += adv; pa2 += adv; pb1 += adv; pb2 += adv;

      // --- neighbor window float4s from adjacent lanes (DS pipe) ---
      const float aAx = __shfl_up(aB.x, 1);
      const float aAy = __shfl_up(aB.y, 1);
      const float aAz = __shfl_up(aB.z, 1);
      const float aAw = __shfl_up(aB.w, 1);
      const float aCx = __shfl_down(aB.x, 1);
      const float aCy = __shfl_down(aB.y, 1);
      const float aCz = __shfl_down(aB.z, 1);
      const float aCw = __shfl_down(aB.w, 1);
      const float bAx = __shfl_up(bB.x, 1);
      const float bAy = __shfl_up(bB.y, 1);
      const float bAz = __shfl_up(bB.z, 1);
      const float bAw = __shfl_up(bB.w, 1);
      const float bCx = __shfl_down(bB.x, 1);
      const float bCy = __shfl_down(bB.y, 1);
      const float bCz = __shfl_down(bB.z, 1);
      const float bCw = __shfl_down(bB.w, 1);

      // --- channel a ---
      alignas(16) float f2ra[12];
      f2ra[0] = vA ? aAx : 0.f;
      f2ra[1] = vA ? aAy : 0.f;
      f2ra[2] = vA ? aAz : 0.f;
      f2ra[3] = vA ? aAw : 0.f;
      f2ra[4] = aB.x; f2ra[5] = aB.y; f2ra[6] = aB.z; f2ra[7] = aB.w;
      f2ra[8]  = vC ? aCx : 0.f;
      f2ra[9]  = vC ? aCy : 0.f;
      f2ra[10] = vC ? aCz : 0.f;
      f2ra[11] = vC ? aCw : 0.f;
      alignas(16) const float xxa[4] = {xa.x, xa.y, xa.z, xa.w};

#pragma unroll
      for (int j = 0; j < 9; ++j) {
        const float wj = ca[j];
#pragma unroll
        for (int k = 0; k < 4; ++k) acc[j][k] += wj * (xxa[k] * f2ra[k + j]);
      }

      // --- channel b (c+64) ---
      alignas(16) float f2rb[12];
      f2rb[0] = vA ? bAx : 0.f;
      f2rb[1] = vA ? bAy : 0.f;
      f2rb[2] = vA ? bAz : 0.f;
      f2rb[3] = vA ? bAw : 0.f;
      f2rb[4] = bB.x; f2rb[5] = bB.y; f2rb[6] = bB.z; f2rb[7] = bB.w;
      f2rb[8]  = vC ? bCx : 0.f;
      f2rb[9]  = vC ? bCy : 0.f;
      f2rb[10] = vC ? bCz : 0.f;
      f2rb[11] = vC ? bCw : 0.f;
      alignas(16) const float xxb[4] = {xb.x, xb.y, xb.z, xb.w};

#pragma unroll
      for (int j = 0; j < 9; ++j) {
        const float wj = cb[j];
#pragma unroll
        for (int k = 0; k < 4; ++k) acc[j][k] += wj * (xxb[k] * f2rb[k + j]);
      }
    }
  }

  // --- end-only cross-half reduction (one barrier, conflict-free) ---
  __shared__ float4 red[9][64];                 // 9,216 B
  if (wv == 1) {
#pragma unroll
    for (int j = 0; j < 9; ++j)
      red[j][lane] = make_float4(acc[j][0], acc[j][1], acc[j][2], acc[j][3]);
  }
  __syncthreads();

  if (wv == 0) {
    const float inv = 1.0f / 256.0f;
#pragma unroll
    for (int j = 0; j < 9; ++j) {
      const float4 p = red[j][lane];
      float4 o;
      o.x = (acc[j][0] + p.x) * inv;
      o.y = (acc[j][1] + p.y) * inv;
      o.z = (acc[j][2] + p.z) * inv;
      o.w = (acc[j][3] + p.w) * inv;
      *(float4*)(out + (((size_t)(b * 81 + i * 9 + j) * 64 + h) << 7) + w0) = o;
    }
  }
}

// ---------------------------------------------------------------------------
extern "C" void kernel_launch(void* const* d_in, const int* in_sizes, int n_in,
                              void* d_out, int out_size, void* d_ws, size_t ws_size,
                              hipStream_t stream) {
  const float* feat1 = (const float*)d_in[0];
  const float* feat2 = (const float*)d_in[1];
  const float* w1    = (const float*)d_in[2];
  const float* b1    = (const float*)d_in[3];
  const float* w2    = (const float*)d_in[4];
  const float* b2    = (const float*)d_in[5];
  float* out = (float*)d_out;

  float* pooled = (float*)d_ws;                 // 82,944 floats
  float* At     = pooled + 82944;               // 82,944 floats

  corr_pool_kernel<<<1024, 576, 0, stream>>>(feat1, feat2, pooled);
  mlp_kernel<<<4 * 81, 256, 0, stream>>>(pooled, w1, b1, w2, b2, At);
  out_kernel<<<1152, 128, 0, stream>>>(feat1, feat2, At, out);
}